// Round 7
// baseline (4089.647 us; speedup 1.0000x reference)
//
#include <hip/hip_runtime.h>
#include <math.h>

#define BB 64
#define TT 512
#define FF 512
#define DIN 1024
#define HH 1024
#define G4 4096
#define DOUT 128

typedef _Float16 f16;
typedef _Float16 f16x4 __attribute__((ext_vector_type(4)));
typedef _Float16 f16x8 __attribute__((ext_vector_type(8)));
typedef float f32x4 __attribute__((ext_vector_type(4)));

// A-fragment-linear layout for a [64 x 1024] fp16 activation matrix:
//   element (m, k) -> ((k>>5)*4 + (m>>4))*512 + ((((k>>3)&3)<<4) | (m&15))*8 + (k&7)
__device__ __forceinline__ size_t afrag_off(int m, int k) {
    return (size_t)(((k >> 5) * 4 + (m >> 4)) * 512 + (((((k >> 3) & 3) << 4) | (m & 15)) * 8) + (k & 7));
}

// agent-scope write-through 16-B store (IF authoritative for cross-XCD readers)
__device__ __forceinline__ void store_b128_sc1(void* p, f32x4 v) {
    asm volatile("global_store_dwordx4 %0, %1, off sc1" :: "v"(p), "v"(v) : "memory");
}

// ---------------------------------------------------------------------------
// Pack cat(W,U) [2048 x 4096] fp32 -> fp16 B-fragment-linear, z-cols reordered
// as col' = j*4 + g. Per (cg, kstep) a contiguous 1KB fragment tile.
// ---------------------------------------------------------------------------
__global__ __launch_bounds__(64) void k_pack(
    const float* __restrict__ W, const float* __restrict__ U, f16* __restrict__ out)
{
    const int kstep = blockIdx.x, cg = blockIdx.y, l = threadIdx.x;
    const int n = l & 15, q = l >> 4;
    const int stdcol = (n & 3) * HH + cg * 4 + (n >> 2);
    f16x8 v;
#pragma unroll
    for (int e = 0; e < 8; ++e) {
        int k = kstep * 32 + q * 8 + e;
        float s = (k < DIN) ? W[(size_t)k * G4 + stdcol] : U[(size_t)(k - DIN) * G4 + stdcol];
        v[e] = (f16)s;
    }
    *(f16x8*)(out + ((size_t)(cg * 64 + kstep) * 64 + l) * 8) = v;
}

// ---------------------------------------------------------------------------
// Pack Wi [512 x 1024] fp32 -> fp16 B-frag (no gate reorder). Tile (nt, kstep).
// ---------------------------------------------------------------------------
__global__ __launch_bounds__(64) void k_pack_wi(
    const float* __restrict__ Wi, f16* __restrict__ out)
{
    const int kstep = blockIdx.x;   // 0..15
    const int nt    = blockIdx.y;   // 0..63
    const int l = threadIdx.x;
    const int n = nt * 16 + (l & 15), q = l >> 4;
    f16x8 v;
#pragma unroll
    for (int e = 0; e < 8; ++e)
        v[e] = (f16)Wi[(size_t)(kstep * 32 + q * 8 + e) * DIN + n];
    *(f16x8*)(out + ((size_t)(nt * 16 + kstep) * 64 + l) * 8) = v;
}

// ---------------------------------------------------------------------------
// MFMA input dense: XinF[t] = tanh(x[:,t,:] @ Wi + bi), f16 A-frag layout.
// One block per t; stage x[:,t,:] as f16 in LDS [64][520]; 4 waves x 4 N-groups.
// ---------------------------------------------------------------------------
__global__ __launch_bounds__(256) void k_dense_in2(
    const float* __restrict__ x, const f16* __restrict__ pWi,
    const float* __restrict__ bi, f16* __restrict__ XinF)
{
    extern __shared__ f16 xs[];   // 64 x 520 = 66560 B
    const int t = blockIdx.x;
    const int tid = threadIdx.x;

#pragma unroll
    for (int it = 0; it < 32; ++it) {
        int idx = tid + it * 256;          // 0..8191 float4s
        int r = idx >> 7, c4 = idx & 127;
        float4 v = *(const float4*)(x + ((size_t)r * TT + t) * FF + c4 * 4);
        f16x4 hv = {(f16)v.x, (f16)v.y, (f16)v.z, (f16)v.w};
        *(f16x4*)(xs + (size_t)r * 520 + c4 * 4) = hv;
    }
    __syncthreads();

    const int w = tid >> 6, lane = tid & 63;
    const int col = lane & 15, rq = lane >> 4;
#pragma unroll 1
    for (int g = 0; g < 4; ++g) {
        f32x4 acc[4][4];
#pragma unroll
        for (int a = 0; a < 4; ++a)
#pragma unroll
            for (int b = 0; b < 4; ++b) acc[a][b] = (f32x4){0.f, 0.f, 0.f, 0.f};
#pragma unroll 2
        for (int ks2 = 0; ks2 < 16; ++ks2) {
            f16x8 bf[4];
#pragma unroll
            for (int nn = 0; nn < 4; ++nn)
                bf[nn] = *(const f16x8*)(pWi + ((size_t)((w * 16 + g * 4 + nn) * 16 + ks2) * 64 + lane) * 8);
#pragma unroll
            for (int mt = 0; mt < 4; ++mt) {
                f16x8 af = *(const f16x8*)(xs + (size_t)(mt * 16 + col) * 520 + ks2 * 32 + rq * 8);
#pragma unroll
                for (int nn = 0; nn < 4; ++nn)
                    acc[mt][nn] = __builtin_amdgcn_mfma_f32_16x16x32_f16(af, bf[nn], acc[mt][nn], 0, 0, 0);
            }
        }
#pragma unroll
        for (int nn = 0; nn < 4; ++nn) {
            const int j = (w * 16 + g * 4 + nn) * 16 + col;
            const float bb = bi[j];
#pragma unroll
            for (int mt = 0; mt < 4; ++mt)
#pragma unroll
                for (int r = 0; r < 4; ++r)
                    XinF[(size_t)t * (BB * DIN) + afrag_off(mt * 16 + rq * 4 + r, j)]
                        = (f16)tanhf(acc[mt][nn][r] + bb);
        }
    }
}

// ---------------------------------------------------------------------------
// Persistent kernel, 256 blocks x 512 threads (1 block/CU).
// lay = bid&1, cgb = bid>>1 (8 hidden units). Weights in LDS once.
// Sync (round 7): spread-store arrivals (each block plain-stores its own word
// fl[cgb] = p+1; NO RMW -- round 6 proved contended fetch_add costs +9%) with
// DIRECT consumer polling (no aggregator, no go hop): consumer wave0 polls
// all 128 L0 arrival words; L1's second wave polls the 128 L1 words; then
// __syncthreads. This removes the aggregator's detect-poll + publish legs and
// its straggler duty from every phase.
// CODEGEN RULE (rounds 1/2/5 failures): phase body stays textually in the
// round-0 shape -- if(pre){load batch} gate if(!pre){load batch} mfma-loop --
// at top level. The wave-poll loop is the same shape as round 3's aggregator
// poll (codegen-proven alongside VGPR 104).
// h: write-once history, sc1 write-through 16-B stores. Cell state c in regs.
// Epilogue: conflict-free buf[4 kq][64 rows][stride 20] f32, repack folded
// into n==1 reduce (validated rounds 1-3).
// ---------------------------------------------------------------------------
__global__ __launch_bounds__(512, 2) void k_persist(
    const f16* __restrict__ XinF,
    f16* __restrict__ h0b_, f16* __restrict__ h1b_,
    const f16* __restrict__ pW0, const f16* __restrict__ pW1,
    const float* __restrict__ b0, const float* __restrict__ b1,
    unsigned* __restrict__ flags)
{
    extern __shared__ char smem[];
    f16*   bsh  = (f16*)smem;                    // 131072 B weight fragments
    float* buf  = (float*)(smem + 131072);       // 4 x 64 x 20 f32 = 20480 B
    f16*   hrow = (f16*)(smem + 131072 + 20480); // 64 x 8 f16 = 1024 B

    const int lay = blockIdx.x & 1;
    const int cgb = blockIdx.x >> 1;
    const int tid = threadIdx.x;
    const int wv = tid >> 6, lane = tid & 63;
    const int kq = wv >> 1, mh = wv & 1;

    unsigned* fl0 = flags;                       // L0 arrival words [128]
    unsigned* fl1 = flags + 1024;                // L1 arrival words [128]
    unsigned* flOwn = lay ? fl1 : fl0;

    // ---- stage this block's weight slice into LDS (once) ----
    {
        const f16x8* s8 = (const f16x8*)((lay ? pW1 : pW0) + (size_t)(cgb * 2) * 64 * 512);
        f16x8* d8 = (f16x8*)bsh;
#pragma unroll
        for (int it = 0; it < 16; ++it) d8[tid + it * 512] = s8[tid + it * 512];
    }

    // ---- epilogue-role constants ----
    const float* bias = lay ? b1 : b0;
    const int erow = tid & 63, ejl = (tid >> 6) & 3;
    float bz[2][4];
    float creg[2] = {0.f, 0.f};
    if (tid < 256) {
#pragma unroll
        for (int n = 0; n < 2; ++n) {
            const int jg = (cgb * 2 + n) * 4 + ejl;
#pragma unroll
            for (int g = 0; g < 4; ++g) bz[n][g] = bias[g * HH + jg];
        }
    }

    const size_t HBUF = (size_t)BB * DIN;
    const f16* bq = bsh + (size_t)(kq * 16 * 64 + lane) * 8;
    const int colw = lane & 15, rg = lane >> 4;
    __syncthreads();

    for (int p = 0; p <= TT; ++p) {
        if (lay == 0 && p == TT) break;          // L0 finished at p=511
        const bool active = lay ? (p >= 1) : true;

        if (active) {
            const f16* Abase;
            if (lay == 0) Abase = (kq < 2) ? (XinF + (size_t)p * HBUF) : (h0b_ + (size_t)p * HBUF);
            else          Abase = (kq < 2) ? (h0b_ + (size_t)p * HBUF) : (h1b_ + (size_t)(p - 1) * HBUF);
            f16* hw = lay ? (h1b_ + (size_t)p * HBUF) : (h0b_ + (size_t)(p + 1) * HBUF);
            const f16* Ap = Abase + (size_t)(((kq & 1) * 64 + mh * 2) * 512) + (size_t)lane * 8;

            f16x8 a0v[16], a1v[16];
            const bool pre = (lay == 0) && (kq < 2);   // Xin is static: safe pre-barrier
            if (pre) {
#pragma unroll
                for (int ii = 0; ii < 16; ++ii) {
                    a0v[ii] = *(const f16x8*)(Ap + (size_t)(ii * 4) * 512);
                    a1v[ii] = *(const f16x8*)(Ap + (size_t)(ii * 4 + 1) * 512);
                }
            }

            // ---- wait for phase inputs (direct polling of arrival words) ----
            if (lay == 0) {
                if (p > 0) {
                    if (tid < 64) {
                        for (;;) {
                            bool ok = (__hip_atomic_load(&fl0[lane], __ATOMIC_RELAXED, __HIP_MEMORY_SCOPE_AGENT) >= (unsigned)p)
                                   && (__hip_atomic_load(&fl0[lane + 64], __ATOMIC_RELAXED, __HIP_MEMORY_SCOPE_AGENT) >= (unsigned)p);
                            if (__all(ok)) break;
                            __builtin_amdgcn_s_sleep(1);
                        }
                    }
                    __syncthreads();
                }
            } else {
                if (tid < 128) {
                    const unsigned* fb = (tid < 64) ? fl0 : fl1;
                    for (;;) {
                        bool ok = (__hip_atomic_load(&fb[lane], __ATOMIC_RELAXED, __HIP_MEMORY_SCOPE_AGENT) >= (unsigned)p)
                               && (__hip_atomic_load(&fb[lane + 64], __ATOMIC_RELAXED, __HIP_MEMORY_SCOPE_AGENT) >= (unsigned)p);
                        if (__all(ok)) break;
                        __builtin_amdgcn_s_sleep(1);
                    }
                }
                __syncthreads();
            }

            if (!pre) {
#pragma unroll
                for (int ii = 0; ii < 16; ++ii) {
                    a0v[ii] = *(const f16x8*)(Ap + (size_t)(ii * 4) * 512);
                    a1v[ii] = *(const f16x8*)(Ap + (size_t)(ii * 4 + 1) * 512);
                }
            }

            f32x4 acc00 = {0.f,0.f,0.f,0.f}, acc01 = {0.f,0.f,0.f,0.f};
            f32x4 acc10 = {0.f,0.f,0.f,0.f}, acc11 = {0.f,0.f,0.f,0.f};
#pragma unroll
            for (int ii = 0; ii < 16; ++ii) {
                f16x8 bb0 = *(const f16x8*)(bq + (size_t)ii * 512);
                f16x8 bb1 = *(const f16x8*)(bq + 32768 + (size_t)ii * 512);
                acc00 = __builtin_amdgcn_mfma_f32_16x16x32_f16(a0v[ii], bb0, acc00, 0, 0, 0);
                acc01 = __builtin_amdgcn_mfma_f32_16x16x32_f16(a0v[ii], bb1, acc01, 0, 0, 0);
                acc10 = __builtin_amdgcn_mfma_f32_16x16x32_f16(a1v[ii], bb0, acc10, 0, 0, 0);
                acc11 = __builtin_amdgcn_mfma_f32_16x16x32_f16(a1v[ii], bb1, acc11, 0, 0, 0);
            }

            // ---- epilogue: two n-rounds over conflict-free buf[kq][row][20] ----
            f16 hvv[2];
#pragma unroll 1
            for (int n = 0; n < 2; ++n) {
                float* t0 = buf + (size_t)kq * 1280 + (size_t)(mh * 32 + rg * 4) * 20 + colw;
#pragma unroll
                for (int r = 0; r < 4; ++r) {
                    t0[r * 20]           = n ? acc01[r] : acc00[r];
                    t0[16 * 20 + r * 20] = n ? acc11[r] : acc10[r];
                }
                __syncthreads();
                if (tid < 256) {
                    f32x4 z = {0.f, 0.f, 0.f, 0.f};
#pragma unroll
                    for (int k2 = 0; k2 < 4; ++k2)
                        z += *(const f32x4*)(buf + (size_t)k2 * 1280 + (size_t)erow * 20 + ejl * 4);
                    const float z0 = z[0] + bz[n][0];
                    const float z1 = z[1] + bz[n][1];
                    const float z2 = z[2] + bz[n][2];
                    const float z3 = z[3] + bz[n][3];
                    const float ig = 1.f / (1.f + expf(-z0));
                    const float fg = 1.f / (1.f + expf(-z1));
                    const float cc = tanhf(z2);
                    const float og = 1.f / (1.f + expf(-z3));
                    const float cn = fg * creg[n] + ig * cc;
                    creg[n] = cn;
                    hvv[n] = (f16)(og * tanhf(cn));
                    if (n == 1) {   // fold repack into the last reduce round
                        hrow[erow * 8 + ejl]     = hvv[0];
                        hrow[erow * 8 + 4 + ejl] = hvv[1];
                    }
                }
                __syncthreads();
            }

            // ---- one 16-B sc1 store per row (wave0 only) ----
            if (tid < 64) {
                f32x4 v = *(f32x4*)(hrow + tid * 8);
                store_b128_sc1(hw + afrag_off(tid, cgb * 8), v);
            }
        }

        // ---- arrival: wave0 drains its h stores, tid0 plain-stores own word ----
        asm volatile("s_waitcnt vmcnt(0)" ::: "memory");
        if (tid == 0)
            __hip_atomic_store(&flOwn[cgb], (unsigned)(p + 1),
                               __ATOMIC_RELAXED, __HIP_MEMORY_SCOPE_AGENT);
    }
}

// ---------------------------------------------------------------------------
// Kernel 3: out[b][o] = tanh(h1[b,:] @ Wo[:,o] + bo[o]); h1 in fp16 A-frag.
// ---------------------------------------------------------------------------
__global__ __launch_bounds__(128) void k_out(
    const f16* __restrict__ h1f, const float* __restrict__ Wo,
    const float* __restrict__ bo, float* __restrict__ out)
{
    __shared__ float hs[HH];
    const int b = blockIdx.x;
    for (int i = threadIdx.x; i < HH; i += 128) hs[i] = (float)h1f[afrag_off(b, i)];
    __syncthreads();
    const int o = threadIdx.x;
    float acc = 0.f;
    for (int k = 0; k < HH; ++k) acc += hs[k] * Wo[k * DOUT + o];
    out[b * DOUT + o] = tanhf(acc + bo[o]);
}

// ---------------------------------------------------------------------------
extern "C" void kernel_launch(void* const* d_in, const int* in_sizes, int n_in,
                              void* d_out, int out_size, void* d_ws, size_t ws_size,
                              hipStream_t stream)
{
    const float* x  = (const float*)d_in[0];
    const float* Wi = (const float*)d_in[1];
    const float* bi = (const float*)d_in[2];
    const float* W0 = (const float*)d_in[3];
    const float* U0 = (const float*)d_in[4];
    const float* b0 = (const float*)d_in[5];
    const float* W1 = (const float*)d_in[6];
    const float* U1 = (const float*)d_in[7];
    const float* b1 = (const float*)d_in[8];
    const float* Wo = (const float*)d_in[9];
    const float* bo = (const float*)d_in[10];
    float* out = (float*)d_out;

    f16* ws16 = (f16*)d_ws;
    const size_t HBUF = (size_t)BB * DIN;          // 65536 f16
    f16* XinF = ws16;                              // 512 bufs
    f16* pW0  = XinF + (size_t)TT * HBUF;
    f16* pW1  = pW0 + (size_t)2048 * G4;
    f16* pWi  = pW1 + (size_t)2048 * G4;           // 512*1024
    f16* h0   = pWi + (size_t)FF * DIN;            // 513 bufs (write-once hist)
    f16* h1   = h0 + (size_t)513 * HBUF;           // 513 bufs
    unsigned* flags = (unsigned*)(h1 + (size_t)513 * HBUF);

    // zero initial h0[-1], h1[-1] and the flag region
    hipMemsetAsync(h0, 0, HBUF * sizeof(f16), stream);
    hipMemsetAsync(h1, 0, HBUF * sizeof(f16), stream);
    hipMemsetAsync(flags, 0, 16384, stream);

    k_pack<<<dim3(64, 256), 64, 0, stream>>>(W0, U0, pW0);
    k_pack<<<dim3(64, 256), 64, 0, stream>>>(W1, U1, pW1);
    k_pack_wi<<<dim3(16, 64), 64, 0, stream>>>(Wi, pWi);

    hipFuncSetAttribute((const void*)k_dense_in2,
                        hipFuncAttributeMaxDynamicSharedMemorySize, 66560);
    k_dense_in2<<<TT, 256, 66560, stream>>>(x, pWi, bi, XinF);

    {
        const int smem_bytes = 131072 + 20480 + 1024;   // 152576 B
        hipFuncSetAttribute((const void*)k_persist,
                            hipFuncAttributeMaxDynamicSharedMemorySize, smem_bytes);
        const f16* XinF_c = XinF;
        const f16* pW0_c = pW0;
        const f16* pW1_c = pW1;
        f16 *h0_v = h0, *h1_v = h1;
        const float *b0_v = b0, *b1_v = b1;
        unsigned* flags_v = flags;
        void* kargs[] = {
            (void*)&XinF_c,
            (void*)&h0_v, (void*)&h1_v,
            (void*)&pW0_c, (void*)&pW1_c,
            (void*)&b0_v, (void*)&b1_v,
            (void*)&flags_v
        };
        hipLaunchCooperativeKernel((void*)k_persist, dim3(256), dim3(512),
                                   kargs, smem_bytes, stream);
    }

    // h1[511] lives at h1 + 512*HBUF
    k_out<<<BB, 128, 0, stream>>>(h1 + (size_t)512 * HBUF, Wo, bo, out);
}

// Round 8
// 3296.444 us; speedup vs baseline: 1.2406x; 1.2406x over previous
//
#include <hip/hip_runtime.h>
#include <math.h>

#define BB 64
#define TT 512
#define FF 512
#define DIN 1024
#define HH 1024
#define G4 4096
#define DOUT 128

typedef _Float16 f16;
typedef _Float16 f16x4 __attribute__((ext_vector_type(4)));
typedef _Float16 f16x8 __attribute__((ext_vector_type(8)));
typedef float f32x4 __attribute__((ext_vector_type(4)));

// A-fragment-linear layout for a [64 x 1024] fp16 activation matrix:
//   element (m, k) -> ((k>>5)*4 + (m>>4))*512 + ((((k>>3)&3)<<4) | (m&15))*8 + (k&7)
__device__ __forceinline__ size_t afrag_off(int m, int k) {
    return (size_t)(((k >> 5) * 4 + (m >> 4)) * 512 + (((((k >> 3) & 3) << 4) | (m & 15)) * 8) + (k & 7));
}

// agent-scope write-through 16-B store (IF authoritative for cross-XCD readers)
__device__ __forceinline__ void store_b128_sc1(void* p, f32x4 v) {
    asm volatile("global_store_dwordx4 %0, %1, off sc1" :: "v"(p), "v"(v) : "memory");
}

// Fast gate math via v_exp_f32 (exp2). Saturation-safe formulations:
//   sigmoid(z) = rcp(1 + exp2(-1.4427 z))   z->+inf: rcp(1)=1; z->-inf: rcp(inf)=0
//   tanh(z)    = 1 - 2 rcp(1 + exp2(2.8854 z))  z->+inf: 1; z->-inf: 1-2 = -1
// Error ~2 ulp of exp2/rcp (~2e-7) vs f16-dominated absmax 3.9e-3: negligible.
__device__ __forceinline__ float fast_sigmoid(float z) {
    return __builtin_amdgcn_rcpf(1.f + __builtin_amdgcn_exp2f(-1.44269504f * z));
}
__device__ __forceinline__ float fast_tanh(float z) {
    return 1.f - 2.f * __builtin_amdgcn_rcpf(1.f + __builtin_amdgcn_exp2f(2.88539008f * z));
}

// ---------------------------------------------------------------------------
// Pack cat(W,U) [2048 x 4096] fp32 -> fp16 B-fragment-linear, z-cols reordered
// as col' = j*4 + g. Per (cg, kstep) a contiguous 1KB fragment tile.
// ---------------------------------------------------------------------------
__global__ __launch_bounds__(64) void k_pack(
    const float* __restrict__ W, const float* __restrict__ U, f16* __restrict__ out)
{
    const int kstep = blockIdx.x, cg = blockIdx.y, l = threadIdx.x;
    const int n = l & 15, q = l >> 4;
    const int stdcol = (n & 3) * HH + cg * 4 + (n >> 2);
    f16x8 v;
#pragma unroll
    for (int e = 0; e < 8; ++e) {
        int k = kstep * 32 + q * 8 + e;
        float s = (k < DIN) ? W[(size_t)k * G4 + stdcol] : U[(size_t)(k - DIN) * G4 + stdcol];
        v[e] = (f16)s;
    }
    *(f16x8*)(out + ((size_t)(cg * 64 + kstep) * 64 + l) * 8) = v;
}

// ---------------------------------------------------------------------------
// Pack Wi [512 x 1024] fp32 -> fp16 B-frag (no gate reorder). Tile (nt, kstep).
// ---------------------------------------------------------------------------
__global__ __launch_bounds__(64) void k_pack_wi(
    const float* __restrict__ Wi, f16* __restrict__ out)
{
    const int kstep = blockIdx.x;   // 0..15
    const int nt    = blockIdx.y;   // 0..63
    const int l = threadIdx.x;
    const int n = nt * 16 + (l & 15), q = l >> 4;
    f16x8 v;
#pragma unroll
    for (int e = 0; e < 8; ++e)
        v[e] = (f16)Wi[(size_t)(kstep * 32 + q * 8 + e) * DIN + n];
    *(f16x8*)(out + ((size_t)(nt * 16 + kstep) * 64 + l) * 8) = v;
}

// ---------------------------------------------------------------------------
// MFMA input dense: XinF[t] = tanh(x[:,t,:] @ Wi + bi), f16 A-frag layout.
// One block per t; stage x[:,t,:] as f16 in LDS [64][520]; 4 waves x 4 N-groups.
// ---------------------------------------------------------------------------
__global__ __launch_bounds__(256) void k_dense_in2(
    const float* __restrict__ x, const f16* __restrict__ pWi,
    const float* __restrict__ bi, f16* __restrict__ XinF)
{
    extern __shared__ f16 xs[];   // 64 x 520 = 66560 B
    const int t = blockIdx.x;
    const int tid = threadIdx.x;

#pragma unroll
    for (int it = 0; it < 32; ++it) {
        int idx = tid + it * 256;          // 0..8191 float4s
        int r = idx >> 7, c4 = idx & 127;
        float4 v = *(const float4*)(x + ((size_t)r * TT + t) * FF + c4 * 4);
        f16x4 hv = {(f16)v.x, (f16)v.y, (f16)v.z, (f16)v.w};
        *(f16x4*)(xs + (size_t)r * 520 + c4 * 4) = hv;
    }
    __syncthreads();

    const int w = tid >> 6, lane = tid & 63;
    const int col = lane & 15, rq = lane >> 4;
#pragma unroll 1
    for (int g = 0; g < 4; ++g) {
        f32x4 acc[4][4];
#pragma unroll
        for (int a = 0; a < 4; ++a)
#pragma unroll
            for (int b = 0; b < 4; ++b) acc[a][b] = (f32x4){0.f, 0.f, 0.f, 0.f};
#pragma unroll 2
        for (int ks2 = 0; ks2 < 16; ++ks2) {
            f16x8 bf[4];
#pragma unroll
            for (int nn = 0; nn < 4; ++nn)
                bf[nn] = *(const f16x8*)(pWi + ((size_t)((w * 16 + g * 4 + nn) * 16 + ks2) * 64 + lane) * 8);
#pragma unroll
            for (int mt = 0; mt < 4; ++mt) {
                f16x8 af = *(const f16x8*)(xs + (size_t)(mt * 16 + col) * 520 + ks2 * 32 + rq * 8);
#pragma unroll
                for (int nn = 0; nn < 4; ++nn)
                    acc[mt][nn] = __builtin_amdgcn_mfma_f32_16x16x32_f16(af, bf[nn], acc[mt][nn], 0, 0, 0);
            }
        }
#pragma unroll
        for (int nn = 0; nn < 4; ++nn) {
            const int j = (w * 16 + g * 4 + nn) * 16 + col;
            const float bb = bi[j];
#pragma unroll
            for (int mt = 0; mt < 4; ++mt)
#pragma unroll
                for (int r = 0; r < 4; ++r)
                    XinF[(size_t)t * (BB * DIN) + afrag_off(mt * 16 + rq * 4 + r, j)]
                        = (f16)fast_tanh(acc[mt][nn][r] + bb);
        }
    }
}

// ---------------------------------------------------------------------------
// Persistent kernel, 256 blocks x 512 threads (1 block/CU).
// lay = bid&1, cgb = bid>>1 (8 hidden units). Weights in LDS once.
// Sync: round-3 protocol EXACTLY (best of R3/R6/R7 map: spread-store arrivals,
// 2-reader aggregator blocks, single read-mostly go word; minimal per-line
// contention). Round-8 deltas, all off the load/MFMA codegen path:
//  - epilogue gates via fast_sigmoid/fast_tanh (v_exp_f32), replacing ~400
//    libm VALU inst/phase on the critical path.
//  - L1 polls goO (binding own-chain gate) BEFORE go0p (pre-satisfied):
//    saves one agent-scope read RT per phase on the L1 chain.
// CODEGEN RULE (rounds 1/2/5): phase body stays textually in the round-0
// shape -- if(pre){load batch} gate if(!pre){load batch} mfma-loop.
// h: write-once history, sc1 write-through 16-B stores. Cell state c in regs.
// Epilogue: conflict-free buf[4 kq][64 rows][stride 20] f32, repack folded
// into n==1 reduce (validated rounds 1-3).
// ---------------------------------------------------------------------------
__global__ __launch_bounds__(512, 2) void k_persist(
    const f16* __restrict__ XinF,
    f16* __restrict__ h0b_, f16* __restrict__ h1b_,
    const f16* __restrict__ pW0, const f16* __restrict__ pW1,
    const float* __restrict__ b0, const float* __restrict__ b1,
    unsigned* __restrict__ flags)
{
    extern __shared__ char smem[];
    f16*   bsh  = (f16*)smem;                    // 131072 B weight fragments
    float* buf  = (float*)(smem + 131072);       // 4 x 64 x 20 f32 = 20480 B
    f16*   hrow = (f16*)(smem + 131072 + 20480); // 64 x 8 f16 = 1024 B

    const int lay = blockIdx.x & 1;
    const int cgb = blockIdx.x >> 1;
    const int tid = threadIdx.x;
    const int wv = tid >> 6, lane = tid & 63;
    const int kq = wv >> 1, mh = wv & 1;

    unsigned* fl   = flags + (lay ? 1024 : 0);   // own-layer arrival words
    unsigned* goO  = flags + 2048 + (lay ? 32 : 0);
    unsigned* go0p = flags + 2048;
    const bool isAgg = (cgb == 0);

    // ---- stage this block's weight slice into LDS (once) ----
    {
        const f16x8* s8 = (const f16x8*)((lay ? pW1 : pW0) + (size_t)(cgb * 2) * 64 * 512);
        f16x8* d8 = (f16x8*)bsh;
#pragma unroll
        for (int it = 0; it < 16; ++it) d8[tid + it * 512] = s8[tid + it * 512];
    }

    // ---- epilogue-role constants ----
    const float* bias = lay ? b1 : b0;
    const int erow = tid & 63, ejl = (tid >> 6) & 3;
    float bz[2][4];
    float creg[2] = {0.f, 0.f};
    if (tid < 256) {
#pragma unroll
        for (int n = 0; n < 2; ++n) {
            const int jg = (cgb * 2 + n) * 4 + ejl;
#pragma unroll
            for (int g = 0; g < 4; ++g) bz[n][g] = bias[g * HH + jg];
        }
    }

    const size_t HBUF = (size_t)BB * DIN;
    const f16* bq = bsh + (size_t)(kq * 16 * 64 + lane) * 8;
    const int colw = lane & 15, rg = lane >> 4;
    __syncthreads();

    for (int p = 0; p <= TT; ++p) {
        if (lay == 0 && p == TT) break;          // L0 finished at p=511
        const bool active = lay ? (p >= 1) : true;

        if (active) {
            const f16* Abase;
            if (lay == 0) Abase = (kq < 2) ? (XinF + (size_t)p * HBUF) : (h0b_ + (size_t)p * HBUF);
            else          Abase = (kq < 2) ? (h0b_ + (size_t)p * HBUF) : (h1b_ + (size_t)(p - 1) * HBUF);
            f16* hw = lay ? (h1b_ + (size_t)p * HBUF) : (h0b_ + (size_t)(p + 1) * HBUF);
            const f16* Ap = Abase + (size_t)(((kq & 1) * 64 + mh * 2) * 512) + (size_t)lane * 8;

            f16x8 a0v[16], a1v[16];
            const bool pre = (lay == 0) && (kq < 2);   // Xin is static: safe pre-barrier
            if (pre) {
#pragma unroll
                for (int ii = 0; ii < 16; ++ii) {
                    a0v[ii] = *(const f16x8*)(Ap + (size_t)(ii * 4) * 512);
                    a1v[ii] = *(const f16x8*)(Ap + (size_t)(ii * 4 + 1) * 512);
                }
            }

            // ---- wait for phase inputs ----
            if (lay == 0) {
                if (p > 0) {
                    if (tid == 0)
                        while (__hip_atomic_load(go0p, __ATOMIC_RELAXED, __HIP_MEMORY_SCOPE_AGENT) < (unsigned)p)
                            __builtin_amdgcn_s_sleep(1);
                    __syncthreads();
                }
            } else {
                if (tid == 0) {
                    // binding own-chain gate FIRST; go0 is pre-satisfied (L0 runs ahead)
                    while (__hip_atomic_load(goO, __ATOMIC_RELAXED, __HIP_MEMORY_SCOPE_AGENT) < (unsigned)p)
                        __builtin_amdgcn_s_sleep(1);
                    while (__hip_atomic_load(go0p, __ATOMIC_RELAXED, __HIP_MEMORY_SCOPE_AGENT) < (unsigned)p)
                        __builtin_amdgcn_s_sleep(1);
                }
                __syncthreads();
            }

            if (!pre) {
#pragma unroll
                for (int ii = 0; ii < 16; ++ii) {
                    a0v[ii] = *(const f16x8*)(Ap + (size_t)(ii * 4) * 512);
                    a1v[ii] = *(const f16x8*)(Ap + (size_t)(ii * 4 + 1) * 512);
                }
            }

            f32x4 acc00 = {0.f,0.f,0.f,0.f}, acc01 = {0.f,0.f,0.f,0.f};
            f32x4 acc10 = {0.f,0.f,0.f,0.f}, acc11 = {0.f,0.f,0.f,0.f};
#pragma unroll
            for (int ii = 0; ii < 16; ++ii) {
                f16x8 bb0 = *(const f16x8*)(bq + (size_t)ii * 512);
                f16x8 bb1 = *(const f16x8*)(bq + 32768 + (size_t)ii * 512);
                acc00 = __builtin_amdgcn_mfma_f32_16x16x32_f16(a0v[ii], bb0, acc00, 0, 0, 0);
                acc01 = __builtin_amdgcn_mfma_f32_16x16x32_f16(a0v[ii], bb1, acc01, 0, 0, 0);
                acc10 = __builtin_amdgcn_mfma_f32_16x16x32_f16(a1v[ii], bb0, acc10, 0, 0, 0);
                acc11 = __builtin_amdgcn_mfma_f32_16x16x32_f16(a1v[ii], bb1, acc11, 0, 0, 0);
            }

            // ---- epilogue: two n-rounds over conflict-free buf[kq][row][20] ----
            f16 hvv[2];
#pragma unroll 1
            for (int n = 0; n < 2; ++n) {
                float* t0 = buf + (size_t)kq * 1280 + (size_t)(mh * 32 + rg * 4) * 20 + colw;
#pragma unroll
                for (int r = 0; r < 4; ++r) {
                    t0[r * 20]           = n ? acc01[r] : acc00[r];
                    t0[16 * 20 + r * 20] = n ? acc11[r] : acc10[r];
                }
                __syncthreads();
                if (tid < 256) {
                    f32x4 z = {0.f, 0.f, 0.f, 0.f};
#pragma unroll
                    for (int k2 = 0; k2 < 4; ++k2)
                        z += *(const f32x4*)(buf + (size_t)k2 * 1280 + (size_t)erow * 20 + ejl * 4);
                    const float z0 = z[0] + bz[n][0];
                    const float z1 = z[1] + bz[n][1];
                    const float z2 = z[2] + bz[n][2];
                    const float z3 = z[3] + bz[n][3];
                    const float ig = fast_sigmoid(z0);
                    const float fg = fast_sigmoid(z1);
                    const float cc = fast_tanh(z2);
                    const float og = fast_sigmoid(z3);
                    const float cn = fg * creg[n] + ig * cc;
                    creg[n] = cn;
                    hvv[n] = (f16)(og * fast_tanh(cn));
                    if (n == 1) {   // fold repack into the last reduce round
                        hrow[erow * 8 + ejl]     = hvv[0];
                        hrow[erow * 8 + 4 + ejl] = hvv[1];
                    }
                }
                __syncthreads();
            }

            // ---- one 16-B sc1 store per row (wave0 only) ----
            if (tid < 64) {
                f32x4 v = *(f32x4*)(hrow + tid * 8);
                store_b128_sc1(hw + afrag_off(tid, cgb * 8), v);
            }
        }

        // ---- arrival: wave0 drains its h stores, tid0 (in wave0) posts flag ----
        asm volatile("s_waitcnt vmcnt(0)" ::: "memory");
        const unsigned tgt = (unsigned)(p + 1);
        if (tid == 0)
            __hip_atomic_store(&fl[cgb], tgt, __ATOMIC_RELAXED, __HIP_MEMORY_SCOPE_AGENT);
        if (isAgg) {
            if (tid < 64) {
                for (;;) {
                    bool ok = (__hip_atomic_load(&fl[lane], __ATOMIC_RELAXED, __HIP_MEMORY_SCOPE_AGENT) >= tgt)
                           && (__hip_atomic_load(&fl[lane + 64], __ATOMIC_RELAXED, __HIP_MEMORY_SCOPE_AGENT) >= tgt);
                    if (__all(ok)) break;
                    __builtin_amdgcn_s_sleep(1);
                }
                if (tid == 0)
                    __hip_atomic_store(goO, tgt, __ATOMIC_RELAXED, __HIP_MEMORY_SCOPE_AGENT);
            }
        }
    }
}

// ---------------------------------------------------------------------------
// Kernel 3: out[b][o] = tanh(h1[b,:] @ Wo[:,o] + bo[o]); h1 in fp16 A-frag.
// ---------------------------------------------------------------------------
__global__ __launch_bounds__(128) void k_out(
    const f16* __restrict__ h1f, const float* __restrict__ Wo,
    const float* __restrict__ bo, float* __restrict__ out)
{
    __shared__ float hs[HH];
    const int b = blockIdx.x;
    for (int i = threadIdx.x; i < HH; i += 128) hs[i] = (float)h1f[afrag_off(b, i)];
    __syncthreads();
    const int o = threadIdx.x;
    float acc = 0.f;
    for (int k = 0; k < HH; ++k) acc += hs[k] * Wo[k * DOUT + o];
    out[b * DOUT + o] = fast_tanh(acc + bo[o]);
}

// ---------------------------------------------------------------------------
extern "C" void kernel_launch(void* const* d_in, const int* in_sizes, int n_in,
                              void* d_out, int out_size, void* d_ws, size_t ws_size,
                              hipStream_t stream)
{
    const float* x  = (const float*)d_in[0];
    const float* Wi = (const float*)d_in[1];
    const float* bi = (const float*)d_in[2];
    const float* W0 = (const float*)d_in[3];
    const float* U0 = (const float*)d_in[4];
    const float* b0 = (const float*)d_in[5];
    const float* W1 = (const float*)d_in[6];
    const float* U1 = (const float*)d_in[7];
    const float* b1 = (const float*)d_in[8];
    const float* Wo = (const float*)d_in[9];
    const float* bo = (const float*)d_in[10];
    float* out = (float*)d_out;

    f16* ws16 = (f16*)d_ws;
    const size_t HBUF = (size_t)BB * DIN;          // 65536 f16
    f16* XinF = ws16;                              // 512 bufs
    f16* pW0  = XinF + (size_t)TT * HBUF;
    f16* pW1  = pW0 + (size_t)2048 * G4;
    f16* pWi  = pW1 + (size_t)2048 * G4;           // 512*1024
    f16* h0   = pWi + (size_t)FF * DIN;            // 513 bufs (write-once hist)
    f16* h1   = h0 + (size_t)513 * HBUF;           // 513 bufs
    unsigned* flags = (unsigned*)(h1 + (size_t)513 * HBUF);

    // zero initial h0[-1], h1[-1] and the flag/go region
    hipMemsetAsync(h0, 0, HBUF * sizeof(f16), stream);
    hipMemsetAsync(h1, 0, HBUF * sizeof(f16), stream);
    hipMemsetAsync(flags, 0, 16384, stream);

    k_pack<<<dim3(64, 256), 64, 0, stream>>>(W0, U0, pW0);
    k_pack<<<dim3(64, 256), 64, 0, stream>>>(W1, U1, pW1);
    k_pack_wi<<<dim3(16, 64), 64, 0, stream>>>(Wi, pWi);

    hipFuncSetAttribute((const void*)k_dense_in2,
                        hipFuncAttributeMaxDynamicSharedMemorySize, 66560);
    k_dense_in2<<<TT, 256, 66560, stream>>>(x, pWi, bi, XinF);

    {
        const int smem_bytes = 131072 + 20480 + 1024;   // 152576 B
        hipFuncSetAttribute((const void*)k_persist,
                            hipFuncAttributeMaxDynamicSharedMemorySize, smem_bytes);
        const f16* XinF_c = XinF;
        const f16* pW0_c = pW0;
        const f16* pW1_c = pW1;
        f16 *h0_v = h0, *h1_v = h1;
        const float *b0_v = b0, *b1_v = b1;
        unsigned* flags_v = flags;
        void* kargs[] = {
            (void*)&XinF_c,
            (void*)&h0_v, (void*)&h1_v,
            (void*)&pW0_c, (void*)&pW1_c,
            (void*)&b0_v, (void*)&b1_v,
            (void*)&flags_v
        };
        hipLaunchCooperativeKernel((void*)k_persist, dim3(256), dim3(512),
                                   kargs, smem_bytes, stream);
    }

    // h1[511] lives at h1 + 512*HBUF
    k_out<<<BB, 128, 0, stream>>>(h1 + (size_t)512 * HBUF, Wo, bo, out);
}

// Round 9
// 3123.650 us; speedup vs baseline: 1.3093x; 1.0553x over previous
//
#include <hip/hip_runtime.h>
#include <math.h>

#define BB 64
#define TT 512
#define FF 512
#define DIN 1024
#define HH 1024
#define G4 4096
#define DOUT 128

typedef _Float16 f16;
typedef _Float16 f16x4 __attribute__((ext_vector_type(4)));
typedef _Float16 f16x8 __attribute__((ext_vector_type(8)));
typedef float f32x4 __attribute__((ext_vector_type(4)));

// A-fragment-linear layout for a [64 x 1024] fp16 activation matrix:
//   element (m, k) -> ((k>>5)*4 + (m>>4))*512 + ((((k>>3)&3)<<4) | (m&15))*8 + (k&7)
__device__ __forceinline__ size_t afrag_off(int m, int k) {
    return (size_t)(((k >> 5) * 4 + (m >> 4)) * 512 + (((((k >> 3) & 3) << 4) | (m & 15)) * 8) + (k & 7));
}

// agent-scope write-through 16-B store (IF authoritative for cross-XCD readers)
__device__ __forceinline__ void store_b128_sc1(void* p, f32x4 v) {
    asm volatile("global_store_dwordx4 %0, %1, off sc1" :: "v"(p), "v"(v) : "memory");
}

// Fast gate math via v_exp_f32 (exp2). Saturation-safe formulations:
//   sigmoid(z) = rcp(1 + exp2(-1.4427 z))   z->+inf: rcp(1)=1; z->-inf: rcp(inf)=0
//   tanh(z)    = 1 - 2 rcp(1 + exp2(2.8854 z))  z->+inf: 1; z->-inf: 1-2 = -1
// Error ~2 ulp of exp2/rcp (~2e-7) vs f16-dominated absmax 3.9e-3: negligible.
// Validated round 8: -300us, absmax unchanged.
__device__ __forceinline__ float fast_sigmoid(float z) {
    return __builtin_amdgcn_rcpf(1.f + __builtin_amdgcn_exp2f(-1.44269504f * z));
}
__device__ __forceinline__ float fast_tanh(float z) {
    return 1.f - 2.f * __builtin_amdgcn_rcpf(1.f + __builtin_amdgcn_exp2f(2.88539008f * z));
}

// ---------------------------------------------------------------------------
// Pack cat(W,U) [2048 x 4096] fp32 -> fp16 B-fragment-linear, z-cols reordered
// as col' = j*4 + g. Per (cg, kstep) a contiguous 1KB fragment tile.
// ---------------------------------------------------------------------------
__global__ __launch_bounds__(64) void k_pack(
    const float* __restrict__ W, const float* __restrict__ U, f16* __restrict__ out)
{
    const int kstep = blockIdx.x, cg = blockIdx.y, l = threadIdx.x;
    const int n = l & 15, q = l >> 4;
    const int stdcol = (n & 3) * HH + cg * 4 + (n >> 2);
    f16x8 v;
#pragma unroll
    for (int e = 0; e < 8; ++e) {
        int k = kstep * 32 + q * 8 + e;
        float s = (k < DIN) ? W[(size_t)k * G4 + stdcol] : U[(size_t)(k - DIN) * G4 + stdcol];
        v[e] = (f16)s;
    }
    *(f16x8*)(out + ((size_t)(cg * 64 + kstep) * 64 + l) * 8) = v;
}

// ---------------------------------------------------------------------------
// Pack Wi [512 x 1024] fp32 -> fp16 B-frag (no gate reorder). Tile (nt, kstep).
// ---------------------------------------------------------------------------
__global__ __launch_bounds__(64) void k_pack_wi(
    const float* __restrict__ Wi, f16* __restrict__ out)
{
    const int kstep = blockIdx.x;   // 0..15
    const int nt    = blockIdx.y;   // 0..63
    const int l = threadIdx.x;
    const int n = nt * 16 + (l & 15), q = l >> 4;
    f16x8 v;
#pragma unroll
    for (int e = 0; e < 8; ++e)
        v[e] = (f16)Wi[(size_t)(kstep * 32 + q * 8 + e) * DIN + n];
    *(f16x8*)(out + ((size_t)(nt * 16 + kstep) * 64 + l) * 8) = v;
}

// ---------------------------------------------------------------------------
// MFMA input dense: XinF[t] = tanh(x[:,t,:] @ Wi + bi), f16 A-frag layout.
// One block per t; stage x[:,t,:] as f16 in LDS [64][520]; 4 waves x 4 N-groups.
// ---------------------------------------------------------------------------
__global__ __launch_bounds__(256) void k_dense_in2(
    const float* __restrict__ x, const f16* __restrict__ pWi,
    const float* __restrict__ bi, f16* __restrict__ XinF)
{
    extern __shared__ f16 xs[];   // 64 x 520 = 66560 B
    const int t = blockIdx.x;
    const int tid = threadIdx.x;

#pragma unroll
    for (int it = 0; it < 32; ++it) {
        int idx = tid + it * 256;          // 0..8191 float4s
        int r = idx >> 7, c4 = idx & 127;
        float4 v = *(const float4*)(x + ((size_t)r * TT + t) * FF + c4 * 4);
        f16x4 hv = {(f16)v.x, (f16)v.y, (f16)v.z, (f16)v.w};
        *(f16x4*)(xs + (size_t)r * 520 + c4 * 4) = hv;
    }
    __syncthreads();

    const int w = tid >> 6, lane = tid & 63;
    const int col = lane & 15, rq = lane >> 4;
#pragma unroll 1
    for (int g = 0; g < 4; ++g) {
        f32x4 acc[4][4];
#pragma unroll
        for (int a = 0; a < 4; ++a)
#pragma unroll
            for (int b = 0; b < 4; ++b) acc[a][b] = (f32x4){0.f, 0.f, 0.f, 0.f};
#pragma unroll 2
        for (int ks2 = 0; ks2 < 16; ++ks2) {
            f16x8 bf[4];
#pragma unroll
            for (int nn = 0; nn < 4; ++nn)
                bf[nn] = *(const f16x8*)(pWi + ((size_t)((w * 16 + g * 4 + nn) * 16 + ks2) * 64 + lane) * 8);
#pragma unroll
            for (int mt = 0; mt < 4; ++mt) {
                f16x8 af = *(const f16x8*)(xs + (size_t)(mt * 16 + col) * 520 + ks2 * 32 + rq * 8);
#pragma unroll
                for (int nn = 0; nn < 4; ++nn)
                    acc[mt][nn] = __builtin_amdgcn_mfma_f32_16x16x32_f16(af, bf[nn], acc[mt][nn], 0, 0, 0);
            }
        }
#pragma unroll
        for (int nn = 0; nn < 4; ++nn) {
            const int j = (w * 16 + g * 4 + nn) * 16 + col;
            const float bb = bi[j];
#pragma unroll
            for (int mt = 0; mt < 4; ++mt)
#pragma unroll
                for (int r = 0; r < 4; ++r)
                    XinF[(size_t)t * (BB * DIN) + afrag_off(mt * 16 + rq * 4 + r, j)]
                        = (f16)fast_tanh(acc[mt][nn][r] + bb);
        }
    }
}

// ---------------------------------------------------------------------------
// Persistent kernel, 256 blocks x 512 threads (1 block/CU).
// lay = bid&1, cgb = bid>>1 (8 hidden units). Weights in LDS once.
// Sync: round-3 protocol (best of R3/R6/R7 map: spread-store arrivals,
// 2-reader aggregator blocks, single read-mostly go word).
// Round-9 delta (L1-chain only, tid0-scalar): L1's two gate polls merged into
// ONE loop issuing BOTH loads per iteration -> latency max(RT,RT) not RT+RT.
// R8's sequential loops paid a full agent-scope RT for the pre-satisfied go0p
// check AFTER goO fired, on the binding L1 chain, every phase.
// CODEGEN RULE (rounds 1/2/5): phase body stays textually in the round-0
// shape -- if(pre){load batch} gate if(!pre){load batch} mfma-loop.
// h: write-once history, sc1 write-through 16-B stores. Cell state c in regs.
// Epilogue: conflict-free buf[4 kq][64 rows][stride 20] f32, fast gate math
// (validated R8: -300us), repack folded into n==1 reduce.
// ---------------------------------------------------------------------------
__global__ __launch_bounds__(512, 2) void k_persist(
    const f16* __restrict__ XinF,
    f16* __restrict__ h0b_, f16* __restrict__ h1b_,
    const f16* __restrict__ pW0, const f16* __restrict__ pW1,
    const float* __restrict__ b0, const float* __restrict__ b1,
    unsigned* __restrict__ flags)
{
    extern __shared__ char smem[];
    f16*   bsh  = (f16*)smem;                    // 131072 B weight fragments
    float* buf  = (float*)(smem + 131072);       // 4 x 64 x 20 f32 = 20480 B
    f16*   hrow = (f16*)(smem + 131072 + 20480); // 64 x 8 f16 = 1024 B

    const int lay = blockIdx.x & 1;
    const int cgb = blockIdx.x >> 1;
    const int tid = threadIdx.x;
    const int wv = tid >> 6, lane = tid & 63;
    const int kq = wv >> 1, mh = wv & 1;

    unsigned* fl   = flags + (lay ? 1024 : 0);   // own-layer arrival words
    unsigned* goO  = flags + 2048 + (lay ? 32 : 0);
    unsigned* go0p = flags + 2048;
    const bool isAgg = (cgb == 0);

    // ---- stage this block's weight slice into LDS (once) ----
    {
        const f16x8* s8 = (const f16x8*)((lay ? pW1 : pW0) + (size_t)(cgb * 2) * 64 * 512);
        f16x8* d8 = (f16x8*)bsh;
#pragma unroll
        for (int it = 0; it < 16; ++it) d8[tid + it * 512] = s8[tid + it * 512];
    }

    // ---- epilogue-role constants ----
    const float* bias = lay ? b1 : b0;
    const int erow = tid & 63, ejl = (tid >> 6) & 3;
    float bz[2][4];
    float creg[2] = {0.f, 0.f};
    if (tid < 256) {
#pragma unroll
        for (int n = 0; n < 2; ++n) {
            const int jg = (cgb * 2 + n) * 4 + ejl;
#pragma unroll
            for (int g = 0; g < 4; ++g) bz[n][g] = bias[g * HH + jg];
        }
    }

    const size_t HBUF = (size_t)BB * DIN;
    const f16* bq = bsh + (size_t)(kq * 16 * 64 + lane) * 8;
    const int colw = lane & 15, rg = lane >> 4;
    __syncthreads();

    for (int p = 0; p <= TT; ++p) {
        if (lay == 0 && p == TT) break;          // L0 finished at p=511
        const bool active = lay ? (p >= 1) : true;

        if (active) {
            const f16* Abase;
            if (lay == 0) Abase = (kq < 2) ? (XinF + (size_t)p * HBUF) : (h0b_ + (size_t)p * HBUF);
            else          Abase = (kq < 2) ? (h0b_ + (size_t)p * HBUF) : (h1b_ + (size_t)(p - 1) * HBUF);
            f16* hw = lay ? (h1b_ + (size_t)p * HBUF) : (h0b_ + (size_t)(p + 1) * HBUF);
            const f16* Ap = Abase + (size_t)(((kq & 1) * 64 + mh * 2) * 512) + (size_t)lane * 8;

            f16x8 a0v[16], a1v[16];
            const bool pre = (lay == 0) && (kq < 2);   // Xin is static: safe pre-barrier
            if (pre) {
#pragma unroll
                for (int ii = 0; ii < 16; ++ii) {
                    a0v[ii] = *(const f16x8*)(Ap + (size_t)(ii * 4) * 512);
                    a1v[ii] = *(const f16x8*)(Ap + (size_t)(ii * 4 + 1) * 512);
                }
            }

            // ---- wait for phase inputs ----
            if (lay == 0) {
                if (p > 0) {
                    if (tid == 0)
                        while (__hip_atomic_load(go0p, __ATOMIC_RELAXED, __HIP_MEMORY_SCOPE_AGENT) < (unsigned)p)
                            __builtin_amdgcn_s_sleep(1);
                    __syncthreads();
                }
            } else {
                if (tid == 0) {
                    // merged dual-poll: both loads in flight each iteration,
                    // total wait = max of the two, not sum (R9 delta)
                    for (;;) {
                        unsigned g1 = __hip_atomic_load(goO,  __ATOMIC_RELAXED, __HIP_MEMORY_SCOPE_AGENT);
                        unsigned g0 = __hip_atomic_load(go0p, __ATOMIC_RELAXED, __HIP_MEMORY_SCOPE_AGENT);
                        if (g1 >= (unsigned)p && g0 >= (unsigned)p) break;
                        __builtin_amdgcn_s_sleep(1);
                    }
                }
                __syncthreads();
            }

            if (!pre) {
#pragma unroll
                for (int ii = 0; ii < 16; ++ii) {
                    a0v[ii] = *(const f16x8*)(Ap + (size_t)(ii * 4) * 512);
                    a1v[ii] = *(const f16x8*)(Ap + (size_t)(ii * 4 + 1) * 512);
                }
            }

            f32x4 acc00 = {0.f,0.f,0.f,0.f}, acc01 = {0.f,0.f,0.f,0.f};
            f32x4 acc10 = {0.f,0.f,0.f,0.f}, acc11 = {0.f,0.f,0.f,0.f};
#pragma unroll
            for (int ii = 0; ii < 16; ++ii) {
                f16x8 bb0 = *(const f16x8*)(bq + (size_t)ii * 512);
                f16x8 bb1 = *(const f16x8*)(bq + 32768 + (size_t)ii * 512);
                acc00 = __builtin_amdgcn_mfma_f32_16x16x32_f16(a0v[ii], bb0, acc00, 0, 0, 0);
                acc01 = __builtin_amdgcn_mfma_f32_16x16x32_f16(a0v[ii], bb1, acc01, 0, 0, 0);
                acc10 = __builtin_amdgcn_mfma_f32_16x16x32_f16(a1v[ii], bb0, acc10, 0, 0, 0);
                acc11 = __builtin_amdgcn_mfma_f32_16x16x32_f16(a1v[ii], bb1, acc11, 0, 0, 0);
            }

            // ---- epilogue: two n-rounds over conflict-free buf[kq][row][20] ----
            f16 hvv[2];
#pragma unroll 1
            for (int n = 0; n < 2; ++n) {
                float* t0 = buf + (size_t)kq * 1280 + (size_t)(mh * 32 + rg * 4) * 20 + colw;
#pragma unroll
                for (int r = 0; r < 4; ++r) {
                    t0[r * 20]           = n ? acc01[r] : acc00[r];
                    t0[16 * 20 + r * 20] = n ? acc11[r] : acc10[r];
                }
                __syncthreads();
                if (tid < 256) {
                    f32x4 z = {0.f, 0.f, 0.f, 0.f};
#pragma unroll
                    for (int k2 = 0; k2 < 4; ++k2)
                        z += *(const f32x4*)(buf + (size_t)k2 * 1280 + (size_t)erow * 20 + ejl * 4);
                    const float z0 = z[0] + bz[n][0];
                    const float z1 = z[1] + bz[n][1];
                    const float z2 = z[2] + bz[n][2];
                    const float z3 = z[3] + bz[n][3];
                    const float ig = fast_sigmoid(z0);
                    const float fg = fast_sigmoid(z1);
                    const float cc = fast_tanh(z2);
                    const float og = fast_sigmoid(z3);
                    const float cn = fg * creg[n] + ig * cc;
                    creg[n] = cn;
                    hvv[n] = (f16)(og * fast_tanh(cn));
                    if (n == 1) {   // fold repack into the last reduce round
                        hrow[erow * 8 + ejl]     = hvv[0];
                        hrow[erow * 8 + 4 + ejl] = hvv[1];
                    }
                }
                __syncthreads();
            }

            // ---- one 16-B sc1 store per row (wave0 only) ----
            if (tid < 64) {
                f32x4 v = *(f32x4*)(hrow + tid * 8);
                store_b128_sc1(hw + afrag_off(tid, cgb * 8), v);
            }
        }

        // ---- arrival: wave0 drains its h stores, tid0 (in wave0) posts flag ----
        asm volatile("s_waitcnt vmcnt(0)" ::: "memory");
        const unsigned tgt = (unsigned)(p + 1);
        if (tid == 0)
            __hip_atomic_store(&fl[cgb], tgt, __ATOMIC_RELAXED, __HIP_MEMORY_SCOPE_AGENT);
        if (isAgg) {
            if (tid < 64) {
                for (;;) {
                    bool ok = (__hip_atomic_load(&fl[lane], __ATOMIC_RELAXED, __HIP_MEMORY_SCOPE_AGENT) >= tgt)
                           && (__hip_atomic_load(&fl[lane + 64], __ATOMIC_RELAXED, __HIP_MEMORY_SCOPE_AGENT) >= tgt);
                    if (__all(ok)) break;
                    __builtin_amdgcn_s_sleep(1);
                }
                if (tid == 0)
                    __hip_atomic_store(goO, tgt, __ATOMIC_RELAXED, __HIP_MEMORY_SCOPE_AGENT);
            }
        }
    }
}

// ---------------------------------------------------------------------------
// Kernel 3: out[b][o] = tanh(h1[b,:] @ Wo[:,o] + bo[o]); h1 in fp16 A-frag.
// ---------------------------------------------------------------------------
__global__ __launch_bounds__(128) void k_out(
    const f16* __restrict__ h1f, const float* __restrict__ Wo,
    const float* __restrict__ bo, float* __restrict__ out)
{
    __shared__ float hs[HH];
    const int b = blockIdx.x;
    for (int i = threadIdx.x; i < HH; i += 128) hs[i] = (float)h1f[afrag_off(b, i)];
    __syncthreads();
    const int o = threadIdx.x;
    float acc = 0.f;
    for (int k = 0; k < HH; ++k) acc += hs[k] * Wo[k * DOUT + o];
    out[b * DOUT + o] = fast_tanh(acc + bo[o]);
}

// ---------------------------------------------------------------------------
extern "C" void kernel_launch(void* const* d_in, const int* in_sizes, int n_in,
                              void* d_out, int out_size, void* d_ws, size_t ws_size,
                              hipStream_t stream)
{
    const float* x  = (const float*)d_in[0];
    const float* Wi = (const float*)d_in[1];
    const float* bi = (const float*)d_in[2];
    const float* W0 = (const float*)d_in[3];
    const float* U0 = (const float*)d_in[4];
    const float* b0 = (const float*)d_in[5];
    const float* W1 = (const float*)d_in[6];
    const float* U1 = (const float*)d_in[7];
    const float* b1 = (const float*)d_in[8];
    const float* Wo = (const float*)d_in[9];
    const float* bo = (const float*)d_in[10];
    float* out = (float*)d_out;

    f16* ws16 = (f16*)d_ws;
    const size_t HBUF = (size_t)BB * DIN;          // 65536 f16
    f16* XinF = ws16;                              // 512 bufs
    f16* pW0  = XinF + (size_t)TT * HBUF;
    f16* pW1  = pW0 + (size_t)2048 * G4;
    f16* pWi  = pW1 + (size_t)2048 * G4;           // 512*1024
    f16* h0   = pWi + (size_t)FF * DIN;            // 513 bufs (write-once hist)
    f16* h1   = h0 + (size_t)513 * HBUF;           // 513 bufs
    unsigned* flags = (unsigned*)(h1 + (size_t)513 * HBUF);

    // zero initial h0[-1], h1[-1] and the flag/go region
    hipMemsetAsync(h0, 0, HBUF * sizeof(f16), stream);
    hipMemsetAsync(h1, 0, HBUF * sizeof(f16), stream);
    hipMemsetAsync(flags, 0, 16384, stream);

    k_pack<<<dim3(64, 256), 64, 0, stream>>>(W0, U0, pW0);
    k_pack<<<dim3(64, 256), 64, 0, stream>>>(W1, U1, pW1);
    k_pack_wi<<<dim3(16, 64), 64, 0, stream>>>(Wi, pWi);

    hipFuncSetAttribute((const void*)k_dense_in2,
                        hipFuncAttributeMaxDynamicSharedMemorySize, 66560);
    k_dense_in2<<<TT, 256, 66560, stream>>>(x, pWi, bi, XinF);

    {
        const int smem_bytes = 131072 + 20480 + 1024;   // 152576 B
        hipFuncSetAttribute((const void*)k_persist,
                            hipFuncAttributeMaxDynamicSharedMemorySize, smem_bytes);
        const f16* XinF_c = XinF;
        const f16* pW0_c = pW0;
        const f16* pW1_c = pW1;
        f16 *h0_v = h0, *h1_v = h1;
        const float *b0_v = b0, *b1_v = b1;
        unsigned* flags_v = flags;
        void* kargs[] = {
            (void*)&XinF_c,
            (void*)&h0_v, (void*)&h1_v,
            (void*)&pW0_c, (void*)&pW1_c,
            (void*)&b0_v, (void*)&b1_v,
            (void*)&flags_v
        };
        hipLaunchCooperativeKernel((void*)k_persist, dim3(256), dim3(512),
                                   kargs, smem_bytes, stream);
    }

    // h1[511] lives at h1 + 512*HBUF
    k_out<<<BB, 128, 0, stream>>>(h1 + (size_t)512 * HBUF, Wo, bo, out);
}

// Round 10
// 2839.995 us; speedup vs baseline: 1.4400x; 1.0999x over previous
//
#include <hip/hip_runtime.h>
#include <math.h>

#define BB 64
#define TT 512
#define FF 512
#define DIN 1024
#define HH 1024
#define G4 4096
#define DOUT 128

typedef _Float16 f16;
typedef _Float16 f16x4 __attribute__((ext_vector_type(4)));
typedef _Float16 f16x8 __attribute__((ext_vector_type(8)));
typedef float f32x4 __attribute__((ext_vector_type(4)));

// A-fragment-linear layout for a [64 x 1024] fp16 activation matrix:
//   element (m, k) -> ((k>>5)*4 + (m>>4))*512 + ((((k>>3)&3)<<4) | (m&15))*8 + (k&7)
__device__ __forceinline__ size_t afrag_off(int m, int k) {
    return (size_t)(((k >> 5) * 4 + (m >> 4)) * 512 + (((((k >> 3) & 3) << 4) | (m & 15)) * 8) + (k & 7));
}

// agent-scope write-through 16-B store (IF authoritative for cross-XCD readers)
__device__ __forceinline__ void store_b128_sc1(void* p, f32x4 v) {
    asm volatile("global_store_dwordx4 %0, %1, off sc1" :: "v"(p), "v"(v) : "memory");
}

// Fast gate math via v_exp_f32 (exp2). Saturation-safe formulations:
//   sigmoid(z) = rcp(1 + exp2(-1.4427 z))   z->+inf: rcp(1)=1; z->-inf: rcp(inf)=0
//   tanh(z)    = 1 - 2 rcp(1 + exp2(2.8854 z))  z->+inf: 1; z->-inf: 1-2 = -1
// Validated round 8: -300us, absmax unchanged.
__device__ __forceinline__ float fast_sigmoid(float z) {
    return __builtin_amdgcn_rcpf(1.f + __builtin_amdgcn_exp2f(-1.44269504f * z));
}
__device__ __forceinline__ float fast_tanh(float z) {
    return 1.f - 2.f * __builtin_amdgcn_rcpf(1.f + __builtin_amdgcn_exp2f(2.88539008f * z));
}

// ---------------------------------------------------------------------------
// Pack cat(W,U) [2048 x 4096] fp32 -> fp16 B-fragment-linear, z-cols reordered
// as col' = j*4 + g. Per (cg, kstep) a contiguous 1KB fragment tile.
// ---------------------------------------------------------------------------
__global__ __launch_bounds__(64) void k_pack(
    const float* __restrict__ W, const float* __restrict__ U, f16* __restrict__ out)
{
    const int kstep = blockIdx.x, cg = blockIdx.y, l = threadIdx.x;
    const int n = l & 15, q = l >> 4;
    const int stdcol = (n & 3) * HH + cg * 4 + (n >> 2);
    f16x8 v;
#pragma unroll
    for (int e = 0; e < 8; ++e) {
        int k = kstep * 32 + q * 8 + e;
        float s = (k < DIN) ? W[(size_t)k * G4 + stdcol] : U[(size_t)(k - DIN) * G4 + stdcol];
        v[e] = (f16)s;
    }
    *(f16x8*)(out + ((size_t)(cg * 64 + kstep) * 64 + l) * 8) = v;
}

// ---------------------------------------------------------------------------
// Pack Wi [512 x 1024] fp32 -> fp16 B-frag (no gate reorder). Tile (nt, kstep).
// ---------------------------------------------------------------------------
__global__ __launch_bounds__(64) void k_pack_wi(
    const float* __restrict__ Wi, f16* __restrict__ out)
{
    const int kstep = blockIdx.x;   // 0..15
    const int nt    = blockIdx.y;   // 0..63
    const int l = threadIdx.x;
    const int n = nt * 16 + (l & 15), q = l >> 4;
    f16x8 v;
#pragma unroll
    for (int e = 0; e < 8; ++e)
        v[e] = (f16)Wi[(size_t)(kstep * 32 + q * 8 + e) * DIN + n];
    *(f16x8*)(out + ((size_t)(nt * 16 + kstep) * 64 + l) * 8) = v;
}

// ---------------------------------------------------------------------------
// MFMA input dense: XinF[t] = tanh(x[:,t,:] @ Wi + bi), f16 A-frag layout.
// One block per t; stage x[:,t,:] as f16 in LDS [64][520]; 4 waves x 4 N-groups.
// ---------------------------------------------------------------------------
__global__ __launch_bounds__(256) void k_dense_in2(
    const float* __restrict__ x, const f16* __restrict__ pWi,
    const float* __restrict__ bi, f16* __restrict__ XinF)
{
    extern __shared__ f16 xs[];   // 64 x 520 = 66560 B
    const int t = blockIdx.x;
    const int tid = threadIdx.x;

#pragma unroll
    for (int it = 0; it < 32; ++it) {
        int idx = tid + it * 256;          // 0..8191 float4s
        int r = idx >> 7, c4 = idx & 127;
        float4 v = *(const float4*)(x + ((size_t)r * TT + t) * FF + c4 * 4);
        f16x4 hv = {(f16)v.x, (f16)v.y, (f16)v.z, (f16)v.w};
        *(f16x4*)(xs + (size_t)r * 520 + c4 * 4) = hv;
    }
    __syncthreads();

    const int w = tid >> 6, lane = tid & 63;
    const int col = lane & 15, rq = lane >> 4;
#pragma unroll 1
    for (int g = 0; g < 4; ++g) {
        f32x4 acc[4][4];
#pragma unroll
        for (int a = 0; a < 4; ++a)
#pragma unroll
            for (int b = 0; b < 4; ++b) acc[a][b] = (f32x4){0.f, 0.f, 0.f, 0.f};
#pragma unroll 2
        for (int ks2 = 0; ks2 < 16; ++ks2) {
            f16x8 bf[4];
#pragma unroll
            for (int nn = 0; nn < 4; ++nn)
                bf[nn] = *(const f16x8*)(pWi + ((size_t)((w * 16 + g * 4 + nn) * 16 + ks2) * 64 + lane) * 8);
#pragma unroll
            for (int mt = 0; mt < 4; ++mt) {
                f16x8 af = *(const f16x8*)(xs + (size_t)(mt * 16 + col) * 520 + ks2 * 32 + rq * 8);
#pragma unroll
                for (int nn = 0; nn < 4; ++nn)
                    acc[mt][nn] = __builtin_amdgcn_mfma_f32_16x16x32_f16(af, bf[nn], acc[mt][nn], 0, 0, 0);
            }
        }
#pragma unroll
        for (int nn = 0; nn < 4; ++nn) {
            const int j = (w * 16 + g * 4 + nn) * 16 + col;
            const float bb = bi[j];
#pragma unroll
            for (int mt = 0; mt < 4; ++mt)
#pragma unroll
                for (int r = 0; r < 4; ++r)
                    XinF[(size_t)t * (BB * DIN) + afrag_off(mt * 16 + rq * 4 + r, j)]
                        = (f16)fast_tanh(acc[mt][nn][r] + bb);
        }
    }
}

// ---------------------------------------------------------------------------
// Persistent kernel, 256 blocks x 512 threads (1 block/CU).
// lay = bid&1, cgb = bid>>1 (8 hidden units). Weights in LDS once.
// Sync: round-3 protocol (spread-store arrivals, 2-reader aggregator blocks,
// single read-mostly go word -- best of the R3/R6/R7 contention map).
// Round-10 delta: EARLY go0 gate for L1 + unified pre=(kq<2). L1's h0-half
// (128 KB of its 256 KB post-gate A-burst) only needs go0 >= p, which L0's
// free-run satisfies ~a phase early -- so gate it cheaply up front and
// pre-load h0 into regs while tid0 polls the binding go1. Halves L1's
// post-gate L2 burst. Codegen-safe: single pre-load site, single gate block,
// single post-load site (round-0 proven shape; unlike R4's nested sites and
// R5's branched copies).
// h: write-once history, sc1 write-through 16-B stores. Cell state c in regs.
// Epilogue: conflict-free buf[4 kq][64 rows][stride 20] f32, fast gate math
// (R8: -300us), repack folded into n==1 reduce.
// ---------------------------------------------------------------------------
__global__ __launch_bounds__(512, 2) void k_persist(
    const f16* __restrict__ XinF,
    f16* __restrict__ h0b_, f16* __restrict__ h1b_,
    const f16* __restrict__ pW0, const f16* __restrict__ pW1,
    const float* __restrict__ b0, const float* __restrict__ b1,
    unsigned* __restrict__ flags)
{
    extern __shared__ char smem[];
    f16*   bsh  = (f16*)smem;                    // 131072 B weight fragments
    float* buf  = (float*)(smem + 131072);       // 4 x 64 x 20 f32 = 20480 B
    f16*   hrow = (f16*)(smem + 131072 + 20480); // 64 x 8 f16 = 1024 B

    const int lay = blockIdx.x & 1;
    const int cgb = blockIdx.x >> 1;
    const int tid = threadIdx.x;
    const int wv = tid >> 6, lane = tid & 63;
    const int kq = wv >> 1, mh = wv & 1;

    unsigned* fl   = flags + (lay ? 1024 : 0);   // own-layer arrival words
    unsigned* goO  = flags + 2048 + (lay ? 32 : 0);
    unsigned* go0p = flags + 2048;
    const bool isAgg = (cgb == 0);

    // ---- stage this block's weight slice into LDS (once) ----
    {
        const f16x8* s8 = (const f16x8*)((lay ? pW1 : pW0) + (size_t)(cgb * 2) * 64 * 512);
        f16x8* d8 = (f16x8*)bsh;
#pragma unroll
        for (int it = 0; it < 16; ++it) d8[tid + it * 512] = s8[tid + it * 512];
    }

    // ---- epilogue-role constants ----
    const float* bias = lay ? b1 : b0;
    const int erow = tid & 63, ejl = (tid >> 6) & 3;
    float bz[2][4];
    float creg[2] = {0.f, 0.f};
    if (tid < 256) {
#pragma unroll
        for (int n = 0; n < 2; ++n) {
            const int jg = (cgb * 2 + n) * 4 + ejl;
#pragma unroll
            for (int g = 0; g < 4; ++g) bz[n][g] = bias[g * HH + jg];
        }
    }

    const size_t HBUF = (size_t)BB * DIN;
    const f16* bq = bsh + (size_t)(kq * 16 * 64 + lane) * 8;
    const int colw = lane & 15, rg = lane >> 4;
    __syncthreads();

    for (int p = 0; p <= TT; ++p) {
        if (lay == 0 && p == TT) break;          // L0 finished at p=511
        const bool active = lay ? (p >= 1) : true;

        if (active) {
            const f16* Abase;
            if (lay == 0) Abase = (kq < 2) ? (XinF + (size_t)p * HBUF) : (h0b_ + (size_t)p * HBUF);
            else          Abase = (kq < 2) ? (h0b_ + (size_t)p * HBUF) : (h1b_ + (size_t)(p - 1) * HBUF);
            f16* hw = lay ? (h1b_ + (size_t)p * HBUF) : (h0b_ + (size_t)(p + 1) * HBUF);
            const f16* Ap = Abase + (size_t)(((kq & 1) * 64 + mh * 2) * 512) + (size_t)lane * 8;

            f16x8 a0v[16], a1v[16];
            const bool pre = (kq < 2);   // L0: static Xin; L1: h0[p] (early-gated)

            // ---- early gate (L1 only): h0[p] readiness. go0 >= p is usually
            //      pre-satisfied since L0 free-runs ahead; near-zero wait. ----
            if (lay == 1) {
                if (tid == 0)
                    while (__hip_atomic_load(go0p, __ATOMIC_RELAXED, __HIP_MEMORY_SCOPE_AGENT) < (unsigned)p)
                        __builtin_amdgcn_s_sleep(1);
                __syncthreads();
            }

            if (pre) {
#pragma unroll
                for (int ii = 0; ii < 16; ++ii) {
                    a0v[ii] = *(const f16x8*)(Ap + (size_t)(ii * 4) * 512);
                    a1v[ii] = *(const f16x8*)(Ap + (size_t)(ii * 4 + 1) * 512);
                }
            }

            // ---- main gate ----
            if (lay == 0) {
                if (p > 0) {
                    if (tid == 0)
                        while (__hip_atomic_load(go0p, __ATOMIC_RELAXED, __HIP_MEMORY_SCOPE_AGENT) < (unsigned)p)
                            __builtin_amdgcn_s_sleep(1);
                    __syncthreads();
                }
            } else {
                if (tid == 0)
                    while (__hip_atomic_load(goO, __ATOMIC_RELAXED, __HIP_MEMORY_SCOPE_AGENT) < (unsigned)p)
                        __builtin_amdgcn_s_sleep(1);
                __syncthreads();
            }

            if (!pre) {
#pragma unroll
                for (int ii = 0; ii < 16; ++ii) {
                    a0v[ii] = *(const f16x8*)(Ap + (size_t)(ii * 4) * 512);
                    a1v[ii] = *(const f16x8*)(Ap + (size_t)(ii * 4 + 1) * 512);
                }
            }

            f32x4 acc00 = {0.f,0.f,0.f,0.f}, acc01 = {0.f,0.f,0.f,0.f};
            f32x4 acc10 = {0.f,0.f,0.f,0.f}, acc11 = {0.f,0.f,0.f,0.f};
#pragma unroll
            for (int ii = 0; ii < 16; ++ii) {
                f16x8 bb0 = *(const f16x8*)(bq + (size_t)ii * 512);
                f16x8 bb1 = *(const f16x8*)(bq + 32768 + (size_t)ii * 512);
                acc00 = __builtin_amdgcn_mfma_f32_16x16x32_f16(a0v[ii], bb0, acc00, 0, 0, 0);
                acc01 = __builtin_amdgcn_mfma_f32_16x16x32_f16(a0v[ii], bb1, acc01, 0, 0, 0);
                acc10 = __builtin_amdgcn_mfma_f32_16x16x32_f16(a1v[ii], bb0, acc10, 0, 0, 0);
                acc11 = __builtin_amdgcn_mfma_f32_16x16x32_f16(a1v[ii], bb1, acc11, 0, 0, 0);
            }

            // ---- epilogue: two n-rounds over conflict-free buf[kq][row][20] ----
            f16 hvv[2];
#pragma unroll 1
            for (int n = 0; n < 2; ++n) {
                float* t0 = buf + (size_t)kq * 1280 + (size_t)(mh * 32 + rg * 4) * 20 + colw;
#pragma unroll
                for (int r = 0; r < 4; ++r) {
                    t0[r * 20]           = n ? acc01[r] : acc00[r];
                    t0[16 * 20 + r * 20] = n ? acc11[r] : acc10[r];
                }
                __syncthreads();
                if (tid < 256) {
                    f32x4 z = {0.f, 0.f, 0.f, 0.f};
#pragma unroll
                    for (int k2 = 0; k2 < 4; ++k2)
                        z += *(const f32x4*)(buf + (size_t)k2 * 1280 + (size_t)erow * 20 + ejl * 4);
                    const float z0 = z[0] + bz[n][0];
                    const float z1 = z[1] + bz[n][1];
                    const float z2 = z[2] + bz[n][2];
                    const float z3 = z[3] + bz[n][3];
                    const float ig = fast_sigmoid(z0);
                    const float fg = fast_sigmoid(z1);
                    const float cc = fast_tanh(z2);
                    const float og = fast_sigmoid(z3);
                    const float cn = fg * creg[n] + ig * cc;
                    creg[n] = cn;
                    hvv[n] = (f16)(og * fast_tanh(cn));
                    if (n == 1) {   // fold repack into the last reduce round
                        hrow[erow * 8 + ejl]     = hvv[0];
                        hrow[erow * 8 + 4 + ejl] = hvv[1];
                    }
                }
                __syncthreads();
            }

            // ---- one 16-B sc1 store per row (wave0 only) ----
            if (tid < 64) {
                f32x4 v = *(f32x4*)(hrow + tid * 8);
                store_b128_sc1(hw + afrag_off(tid, cgb * 8), v);
            }
        }

        // ---- arrival: wave0 drains its h stores, tid0 (in wave0) posts flag ----
        asm volatile("s_waitcnt vmcnt(0)" ::: "memory");
        const unsigned tgt = (unsigned)(p + 1);
        if (tid == 0)
            __hip_atomic_store(&fl[cgb], tgt, __ATOMIC_RELAXED, __HIP_MEMORY_SCOPE_AGENT);
        if (isAgg) {
            if (tid < 64) {
                for (;;) {
                    bool ok = (__hip_atomic_load(&fl[lane], __ATOMIC_RELAXED, __HIP_MEMORY_SCOPE_AGENT) >= tgt)
                           && (__hip_atomic_load(&fl[lane + 64], __ATOMIC_RELAXED, __HIP_MEMORY_SCOPE_AGENT) >= tgt);
                    if (__all(ok)) break;
                    __builtin_amdgcn_s_sleep(1);
                }
                if (tid == 0)
                    __hip_atomic_store(goO, tgt, __ATOMIC_RELAXED, __HIP_MEMORY_SCOPE_AGENT);
            }
        }
    }
}

// ---------------------------------------------------------------------------
// Kernel 3: out[b][o] = tanh(h1[b,:] @ Wo[:,o] + bo[o]); h1 in fp16 A-frag.
// ---------------------------------------------------------------------------
__global__ __launch_bounds__(128) void k_out(
    const f16* __restrict__ h1f, const float* __restrict__ Wo,
    const float* __restrict__ bo, float* __restrict__ out)
{
    __shared__ float hs[HH];
    const int b = blockIdx.x;
    for (int i = threadIdx.x; i < HH; i += 128) hs[i] = (float)h1f[afrag_off(b, i)];
    __syncthreads();
    const int o = threadIdx.x;
    float acc = 0.f;
    for (int k = 0; k < HH; ++k) acc += hs[k] * Wo[k * DOUT + o];
    out[b * DOUT + o] = fast_tanh(acc + bo[o]);
}

// ---------------------------------------------------------------------------
extern "C" void kernel_launch(void* const* d_in, const int* in_sizes, int n_in,
                              void* d_out, int out_size, void* d_ws, size_t ws_size,
                              hipStream_t stream)
{
    const float* x  = (const float*)d_in[0];
    const float* Wi = (const float*)d_in[1];
    const float* bi = (const float*)d_in[2];
    const float* W0 = (const float*)d_in[3];
    const float* U0 = (const float*)d_in[4];
    const float* b0 = (const float*)d_in[5];
    const float* W1 = (const float*)d_in[6];
    const float* U1 = (const float*)d_in[7];
    const float* b1 = (const float*)d_in[8];
    const float* Wo = (const float*)d_in[9];
    const float* bo = (const float*)d_in[10];
    float* out = (float*)d_out;

    f16* ws16 = (f16*)d_ws;
    const size_t HBUF = (size_t)BB * DIN;          // 65536 f16
    f16* XinF = ws16;                              // 512 bufs
    f16* pW0  = XinF + (size_t)TT * HBUF;
    f16* pW1  = pW0 + (size_t)2048 * G4;
    f16* pWi  = pW1 + (size_t)2048 * G4;           // 512*1024
    f16* h0   = pWi + (size_t)FF * DIN;            // 513 bufs (write-once hist)
    f16* h1   = h0 + (size_t)513 * HBUF;           // 513 bufs
    unsigned* flags = (unsigned*)(h1 + (size_t)513 * HBUF);

    // zero initial h0[-1], h1[-1] and the flag/go region
    hipMemsetAsync(h0, 0, HBUF * sizeof(f16), stream);
    hipMemsetAsync(h1, 0, HBUF * sizeof(f16), stream);
    hipMemsetAsync(flags, 0, 16384, stream);

    k_pack<<<dim3(64, 256), 64, 0, stream>>>(W0, U0, pW0);
    k_pack<<<dim3(64, 256), 64, 0, stream>>>(W1, U1, pW1);
    k_pack_wi<<<dim3(16, 64), 64, 0, stream>>>(Wi, pWi);

    hipFuncSetAttribute((const void*)k_dense_in2,
                        hipFuncAttributeMaxDynamicSharedMemorySize, 66560);
    k_dense_in2<<<TT, 256, 66560, stream>>>(x, pWi, bi, XinF);

    {
        const int smem_bytes = 131072 + 20480 + 1024;   // 152576 B
        hipFuncSetAttribute((const void*)k_persist,
                            hipFuncAttributeMaxDynamicSharedMemorySize, smem_bytes);
        const f16* XinF_c = XinF;
        const f16* pW0_c = pW0;
        const f16* pW1_c = pW1;
        f16 *h0_v = h0, *h1_v = h1;
        const float *b0_v = b0, *b1_v = b1;
        unsigned* flags_v = flags;
        void* kargs[] = {
            (void*)&XinF_c,
            (void*)&h0_v, (void*)&h1_v,
            (void*)&pW0_c, (void*)&pW1_c,
            (void*)&b0_v, (void*)&b1_v,
            (void*)&flags_v
        };
        hipLaunchCooperativeKernel((void*)k_persist, dim3(256), dim3(512),
                                   kargs, smem_bytes, stream);
    }

    // h1[511] lives at h1 + 512*HBUF
    k_out<<<BB, 128, 0, stream>>>(h1 + (size_t)512 * HBUF, Wo, bo, out);
}